// Round 1
// baseline (1046.886 us; speedup 1.0000x reference)
//
#include <hip/hip_runtime.h>
#include <cmath>

constexpr int BB = 4, CC = 64, HH = 256, WW = 256;
constexpr int C2ROWS = HH + 1;  // conv2 output rows -1..255 stored at index r+1

// ---------------------------------------------------------------------------
// Kernel 1: per-pixel shift s = 50 / (2 * clip(max_c x, 1, 50))
// ---------------------------------------------------------------------------
__global__ __launch_bounds__(256) void k_depth(const float* __restrict__ x,
                                               float* __restrict__ s) {
  int idx = blockIdx.x * 256 + threadIdx.x;      // b*HH*WW total = 262144
  int b = idx >> 16;                             // HH*WW = 65536
  int hw = idx & 65535;
  const float* px = x + (size_t)b * CC * HH * WW + hw;
  float m = px[0];
#pragma unroll 8
  for (int c = 1; c < CC; ++c) m = fmaxf(m, px[(size_t)c * HH * WW]);
  float d = fminf(fmaxf(m, 1.0f), 50.0f);
  s[idx] = 50.0f / (2.0f * d);
}

// ---------------------------------------------------------------------------
// Kernel 2: C2ext = conv3x3(x2) where x2 = vertical-bilinear warp of x by s.
// Computes output rows r = -1..255 (blockIdx.y - 1). x2 rows are generated
// on the fly during LDS staging (2 global loads + 2 FMA per staged element).
// Block: 256 lanes = columns, 8 output channels (blockIdx.x), batch z.
// ---------------------------------------------------------------------------
__global__ __launch_bounds__(256) void k_lowerconv(const float* __restrict__ x,
                                                   const float* __restrict__ Wt,
                                                   const float* __restrict__ s,
                                                   float* __restrict__ c2) {
  __shared__ float lds[3][WW + 2];
  const int t = threadIdx.x;
  const int og = blockIdx.x;              // output-channel group, 8 ch each
  const int r = (int)blockIdx.y - 1;      // -1..255
  const int b = blockIdx.z;

  if (t < 6) {  // zero-pad LDS columns once
    int j = t >> 1;
    lds[j][(t & 1) ? (WW + 1) : 0] = 0.0f;
  }

  // Per input row j (rows r-1..r+1): warp params, channel-independent.
  int off0[3], off1[3];
  float w0[3], w1[3];
#pragma unroll
  for (int j = 0; j < 3; ++j) {
    int row = r - 1 + j;
    if (row >= 0 && row < HH) {
      float sv = s[(b * HH + row) * WW + t];
      float ys = (float)row - sv;
      float fy = floorf(ys);
      float wf = ys - fy;
      int i0 = (int)fy;                       // in [-25, 254]
      bool v0 = (i0 >= 0) & (i0 < HH);
      bool v1 = (i0 + 1 >= 0) & (i0 + 1 < HH);
      w0[j] = v0 ? 1.0f - wf : 0.0f;
      w1[j] = v1 ? wf : 0.0f;
      int a0 = min(max(i0, 0), HH - 1);
      int a1 = min(max(i0 + 1, 0), HH - 1);
      off0[j] = a0 * WW + t;
      off1[j] = a1 * WW + t;
    } else {  // x2 row out of image -> zero
      w0[j] = 0.0f; w1[j] = 0.0f; off0[j] = t; off1[j] = t;
    }
  }

  float acc[8];
#pragma unroll
  for (int oo = 0; oo < 8; ++oo) acc[oo] = 0.0f;

  for (int c = 0; c < CC; ++c) {
    __syncthreads();
    const float* base = x + (size_t)(b * CC + c) * HH * WW;
#pragma unroll
    for (int j = 0; j < 3; ++j)
      lds[j][t + 1] = w0[j] * base[off0[j]] + w1[j] * base[off1[j]];
    __syncthreads();

    float v[9];
#pragma unroll
    for (int j = 0; j < 3; ++j) {
      v[j * 3 + 0] = lds[j][t + 0];
      v[j * 3 + 1] = lds[j][t + 1];
      v[j * 3 + 2] = lds[j][t + 2];
    }
    const float* wp = Wt + (size_t)((og * 8) * CC + c) * 9;
#pragma unroll
    for (int oo = 0; oo < 8; ++oo) {
      const float* w = wp + (size_t)oo * CC * 9;
      float a = acc[oo];
#pragma unroll
      for (int k = 0; k < 9; ++k) a = fmaf(w[k], v[k], a);
      acc[oo] = a;
    }
  }

#pragma unroll
  for (int oo = 0; oo < 8; ++oo) {
    int o = og * 8 + oo;
    c2[(size_t)((b * CC + o) * C2ROWS + (r + 1)) * WW + t] = acc[oo];
  }
}

// ---------------------------------------------------------------------------
// Kernel 3: upper conv3x3(x) + vertical bilinear sample of C2ext + min.
// ---------------------------------------------------------------------------
__global__ __launch_bounds__(256) void k_final(const float* __restrict__ x,
                                               const float* __restrict__ Wt,
                                               const float* __restrict__ s,
                                               const float* __restrict__ c2,
                                               float* __restrict__ out) {
  __shared__ float lds[3][WW + 2];
  const int t = threadIdx.x;
  const int og = blockIdx.x;
  const int y = blockIdx.y;
  const int b = blockIdx.z;

  if (t < 6) {
    int j = t >> 1;
    lds[j][(t & 1) ? (WW + 1) : 0] = 0.0f;
  }

  int rowok[3], roff[3];
#pragma unroll
  for (int j = 0; j < 3; ++j) {
    int row = y - 1 + j;
    rowok[j] = (row >= 0 && row < HH);
    roff[j] = min(max(row, 0), HH - 1) * WW + t;
  }

  float acc[8];
#pragma unroll
  for (int oo = 0; oo < 8; ++oo) acc[oo] = 0.0f;

  for (int c = 0; c < CC; ++c) {
    __syncthreads();
    const float* base = x + (size_t)(b * CC + c) * HH * WW;
#pragma unroll
    for (int j = 0; j < 3; ++j)
      lds[j][t + 1] = rowok[j] ? base[roff[j]] : 0.0f;
    __syncthreads();

    float v[9];
#pragma unroll
    for (int j = 0; j < 3; ++j) {
      v[j * 3 + 0] = lds[j][t + 0];
      v[j * 3 + 1] = lds[j][t + 1];
      v[j * 3 + 2] = lds[j][t + 2];
    }
    const float* wp = Wt + (size_t)((og * 8) * CC + c) * 9;
#pragma unroll
    for (int oo = 0; oo < 8; ++oo) {
      const float* w = wp + (size_t)oo * CC * 9;
      float a = acc[oo];
#pragma unroll
      for (int k = 0; k < 9; ++k) a = fmaf(w[k], v[k], a);
      acc[oo] = a;
    }
  }

  // lower-branch sample: w0*C2v[fy] + w1*C2v[fy+1], C2v rows -1..255 at +1
  float sv = s[(b * HH + y) * WW + t];
  float ys = (float)y - sv;
  float fy = floorf(ys);
  float wf = ys - fy;
  int i0 = (int)fy;
  bool v0 = (i0 + 1 >= 0) && (i0 + 1 <= HH);   // fy   in [-1, 255]
  bool v1 = (i0 + 2 >= 0) && (i0 + 2 <= HH);   // fy+1 in [-1, 255]
  float lw0 = v0 ? 1.0f - wf : 0.0f;
  float lw1 = v1 ? wf : 0.0f;
  int a0 = min(max(i0 + 1, 0), HH);
  int a1 = min(max(i0 + 2, 0), HH);

#pragma unroll
  for (int oo = 0; oo < 8; ++oo) {
    int o = og * 8 + oo;
    const float* cb = c2 + (size_t)(b * CC + o) * C2ROWS * WW + t;
    float lower = lw0 * cb[(size_t)a0 * WW] + lw1 * cb[(size_t)a1 * WW];
    out[(size_t)((b * CC + o) * HH + y) * WW + t] = fminf(acc[oo], lower);
  }
}

// ---------------------------------------------------------------------------
extern "C" void kernel_launch(void* const* d_in, const int* in_sizes, int n_in,
                              void* d_out, int out_size, void* d_ws, size_t ws_size,
                              hipStream_t stream) {
  const float* x = (const float*)d_in[0];
  const float* Wt = (const float*)d_in[1];
  float* out = (float*)d_out;

  float* s = (float*)d_ws;                          //  1.0 MB
  float* c2 = s + (size_t)BB * HH * WW;             // 64.3 MB (C2ext)

  k_depth<<<dim3(BB * HH * WW / 256), 256, 0, stream>>>(x, s);
  k_lowerconv<<<dim3(8, C2ROWS, BB), 256, 0, stream>>>(x, Wt, s, c2);
  k_final<<<dim3(8, HH, BB), 256, 0, stream>>>(x, Wt, s, c2, out);
}

// Round 2
// 263.818 us; speedup vs baseline: 3.9682x; 3.9682x over previous
//
#include <hip/hip_runtime.h>
#include <cmath>

constexpr int BB = 4, CC = 64, HH = 256, WW = 256;
constexpr int C2R = 257;  // c2 rows -1..255 stored at r+1

typedef short short8 __attribute__((ext_vector_type(8)));
typedef float f32x4 __attribute__((ext_vector_type(4)));
#define MFMA_BF16 __builtin_amdgcn_mfma_f32_16x16x32_bf16

union U16x8 { uint4 v; unsigned short h[8]; };

__device__ inline unsigned short f2bf(float f) {
  unsigned u = __builtin_bit_cast(unsigned, f);
  u += 0x7fffu + ((u >> 16) & 1u);
  return (unsigned short)(u >> 16);
}
__device__ inline float bf2f(unsigned short h) {
  unsigned u = ((unsigned)h) << 16;
  return __builtin_bit_cast(float, u);
}

// ---------------------------------------------------------------------------
// k_pack: block (y, b). NCHW fp32 -> NHWC bf16, fused channel-max -> s.
// ---------------------------------------------------------------------------
__global__ __launch_bounds__(256) void k_pack(const float* __restrict__ x,
                                              float* __restrict__ s,
                                              unsigned short* __restrict__ xn) {
  __shared__ float tile[CC * WW];
  const int t = threadIdx.x, y = blockIdx.x, b = blockIdx.y;
  const float* base = x + (size_t)b * CC * HH * WW + y * WW + t;
  float m = -1e30f;
#pragma unroll 8
  for (int c = 0; c < CC; ++c) {
    float v = base[(size_t)c * HH * WW];
    tile[c * WW + t] = v;
    m = fmaxf(m, v);
  }
  s[(b * HH + y) * WW + t] = 25.0f / fminf(fmaxf(m, 1.0f), 50.0f);
  __syncthreads();
  uint4* xn4 = (uint4*)xn;
#pragma unroll
  for (int g = 0; g < 8; ++g) {
    int px = g * 32 + (t >> 3), c8 = t & 7;
    U16x8 r;
#pragma unroll
    for (int j = 0; j < 8; ++j) r.h[j] = f2bf(tile[(c8 * 8 + j) * WW + px]);
    xn4[(((b * HH + y) * WW + px) * CC + c8 * 8) >> 3] = r.v;
  }
}

// ---------------------------------------------------------------------------
// k_wpack: W [64][64][3][3] fp32 -> bf16 fragments Wp[tap][mtile][kc][lane][8]
// value = W[o = mtile*16 + (lane&15)][cin = kc*32 + (lane>>4)*8 + j][ky][kx]
// ---------------------------------------------------------------------------
__global__ __launch_bounds__(256) void k_wpack(const float* __restrict__ Wt,
                                               unsigned short* __restrict__ Wp) {
  int gid = blockIdx.x * 256 + threadIdx.x;  // 4608 total
  int lane = gid & 63, kc = (gid >> 6) & 1, mt = (gid >> 7) & 3, tap = gid >> 9;
  int o = mt * 16 + (lane & 15);
  int kb = kc * 32 + (lane >> 4) * 8;
  int ky = tap / 3, kx = tap % 3;
  U16x8 r;
#pragma unroll
  for (int j = 0; j < 8; ++j)
    r.h[j] = f2bf(Wt[o * 576 + (kb + j) * 9 + ky * 3 + kx]);
  ((uint4*)Wp)[gid] = r.v;
}

// ---------------------------------------------------------------------------
// Shared LDS chunk addressing: lds[3][258 cols][8 chunks of 8ch], XOR-swizzled.
// ---------------------------------------------------------------------------
__device__ inline int ldsIdx(int ky, int col, int chunk) {
  return (ky * 258 + col) * 8 + (chunk ^ (col & 7));
}

// ---------------------------------------------------------------------------
// k_lower: c2 row r = blockIdx.x - 1 (-1..255). Stage warped rows r-1..r+1
// into LDS (blend on the fly), MFMA conv, store c2 bf16 NHWC.
// D = W (A, ch-major) x X (B, px) : lane holds 4 consecutive ch at one px.
// ---------------------------------------------------------------------------
__global__ __launch_bounds__(256, 1) void k_lower(const unsigned short* __restrict__ xn,
                                                  const unsigned short* __restrict__ Wp,
                                                  const float* __restrict__ s,
                                                  unsigned short* __restrict__ c2) {
  __shared__ uint4 lds[3 * 258 * 8];
  const int t = threadIdx.x;
  const int r = (int)blockIdx.x - 1;
  const int b = blockIdx.y;

  if (t < 48) {  // zero halo cols 0 and 257
    int j = t / 16, e = t % 16;
    int col = (e & 1) ? 257 : 0, c8 = e >> 1;
    lds[ldsIdx(j, col, c8)] = make_uint4(0, 0, 0, 0);
  }

  const uint4* xn4 = (const uint4*)xn;
#pragma unroll
  for (int j = 0; j < 3; ++j) {
    int xrow = r - 1 + j;
#pragma unroll
    for (int g = 0; g < 8; ++g) {
      int col = g * 32 + (t >> 3), c8 = t & 7;
      uint4 val;
      if (xrow < 0 || xrow > 255) {
        val = make_uint4(0, 0, 0, 0);
      } else {
        float sv = s[(b * HH + xrow) * WW + col];
        float ys = (float)xrow - sv;
        float fy = floorf(ys);
        float wfr = ys - fy;
        int i0 = (int)fy;
        float w0 = (i0 >= 0 && i0 < HH) ? 1.0f - wfr : 0.0f;
        float w1 = (i0 + 1 >= 0 && i0 + 1 < HH) ? wfr : 0.0f;
        int a0 = min(max(i0, 0), HH - 1), a1 = min(max(i0 + 1, 0), HH - 1);
        U16x8 u0, u1, rr;
        u0.v = xn4[(((b * HH + a0) * WW + col) * CC + c8 * 8) >> 3];
        u1.v = xn4[(((b * HH + a1) * WW + col) * CC + c8 * 8) >> 3];
#pragma unroll
        for (int k = 0; k < 8; ++k)
          rr.h[k] = f2bf(w0 * bf2f(u0.h[k]) + w1 * bf2f(u1.h[k]));
        val = rr.v;
      }
      lds[ldsIdx(j, col + 1, c8)] = val;
    }
  }
  __syncthreads();

  const int lane = t & 63, w = t >> 6;
  const int p = w >> 1, h = w & 1;
  const int quad = lane >> 4, l15 = lane & 15;

  short8 wf[9][2][2];
  const uint4* wp4 = (const uint4*)Wp;
#pragma unroll
  for (int tap = 0; tap < 9; ++tap)
#pragma unroll
    for (int ct = 0; ct < 2; ++ct)
#pragma unroll
      for (int kc = 0; kc < 2; ++kc)
        wf[tap][ct][kc] = __builtin_bit_cast(
            short8, wp4[((tap * 4 + (2 * p + ct)) * 2 + kc) * 64 + lane]);

#pragma unroll 1
  for (int pt = 0; pt < 8; ++pt) {
    int pxb = h * 128 + pt * 16;
    f32x4 acc0 = {0.f, 0.f, 0.f, 0.f}, acc1 = {0.f, 0.f, 0.f, 0.f};
#pragma unroll
    for (int ky = 0; ky < 3; ++ky)
#pragma unroll
      for (int kx = 0; kx < 3; ++kx) {
        int col = pxb + l15 + kx;
#pragma unroll
        for (int kc = 0; kc < 2; ++kc) {
          short8 a = __builtin_bit_cast(short8, lds[ldsIdx(ky, col, kc * 4 + quad)]);
          acc0 = MFMA_BF16(wf[ky * 3 + kx][0][kc], a, acc0, 0, 0, 0);
          acc1 = MFMA_BF16(wf[ky * 3 + kx][1][kc], a, acc1, 0, 0, 0);
        }
      }
    int px = pxb + l15;
#pragma unroll
    for (int ct = 0; ct < 2; ++ct) {
      f32x4 A = ct ? acc1 : acc0;
      int ch = (2 * p + ct) * 16 + quad * 4;
      unsigned short h0 = f2bf(A[0]), h1 = f2bf(A[1]), h2 = f2bf(A[2]), h3 = f2bf(A[3]);
      uint2 val = make_uint2((unsigned)h0 | ((unsigned)h1 << 16),
                             (unsigned)h2 | ((unsigned)h3 << 16));
      *(uint2*)(c2 + (((size_t)(b * C2R + (r + 1)) * WW + px) * CC + ch)) = val;
    }
  }
}

// ---------------------------------------------------------------------------
// k_final: upper conv (unwarped) + c2 vertical resample + min -> out NCHW f32.
// D = X (A, px-major) x W (B, ch) : lane holds 4 consecutive px at one ch.
// ---------------------------------------------------------------------------
__global__ __launch_bounds__(256, 1) void k_final(const unsigned short* __restrict__ xn,
                                                  const unsigned short* __restrict__ Wp,
                                                  const float* __restrict__ s,
                                                  const unsigned short* __restrict__ c2,
                                                  float* __restrict__ out) {
  __shared__ uint4 lds[3 * 258 * 8];
  const int t = threadIdx.x;
  const int y = blockIdx.x;
  const int b = blockIdx.y;

  if (t < 48) {
    int j = t / 16, e = t % 16;
    int col = (e & 1) ? 257 : 0, c8 = e >> 1;
    lds[ldsIdx(j, col, c8)] = make_uint4(0, 0, 0, 0);
  }

  const uint4* xn4 = (const uint4*)xn;
#pragma unroll
  for (int j = 0; j < 3; ++j) {
    int xrow = y - 1 + j;
#pragma unroll
    for (int g = 0; g < 8; ++g) {
      int col = g * 32 + (t >> 3), c8 = t & 7;
      uint4 val = (xrow < 0 || xrow > 255)
                      ? make_uint4(0, 0, 0, 0)
                      : xn4[(((b * HH + xrow) * WW + col) * CC + c8 * 8) >> 3];
      lds[ldsIdx(j, col + 1, c8)] = val;
    }
  }
  __syncthreads();

  const int lane = t & 63, w = t >> 6;
  const int p = w >> 1, h = w & 1;
  const int quad = lane >> 4, l15 = lane & 15;

  short8 wf[9][2][2];
  const uint4* wp4 = (const uint4*)Wp;
#pragma unroll
  for (int tap = 0; tap < 9; ++tap)
#pragma unroll
    for (int ct = 0; ct < 2; ++ct)
#pragma unroll
      for (int kc = 0; kc < 2; ++kc)
        wf[tap][ct][kc] = __builtin_bit_cast(
            short8, wp4[((tap * 4 + (2 * p + ct)) * 2 + kc) * 64 + lane]);

#pragma unroll 1
  for (int pt = 0; pt < 8; ++pt) {
    int pxb = h * 128 + pt * 16;
    f32x4 acc0 = {0.f, 0.f, 0.f, 0.f}, acc1 = {0.f, 0.f, 0.f, 0.f};
#pragma unroll
    for (int ky = 0; ky < 3; ++ky)
#pragma unroll
      for (int kx = 0; kx < 3; ++kx) {
        int col = pxb + l15 + kx;
#pragma unroll
        for (int kc = 0; kc < 2; ++kc) {
          short8 a = __builtin_bit_cast(short8, lds[ldsIdx(ky, col, kc * 4 + quad)]);
          acc0 = MFMA_BF16(a, wf[ky * 3 + kx][0][kc], acc0, 0, 0, 0);
          acc1 = MFMA_BF16(a, wf[ky * 3 + kx][1][kc], acc1, 0, 0, 0);
        }
      }
    // epilogue: sample c2 at rows floor(y-s), +1; min; store float4 NCHW
    int px0 = pxb + quad * 4;
    f32x4 sv4 = *(const f32x4*)(s + (b * HH + y) * WW + px0);
    float lw0[4], lw1[4];
    int a0i[4], a1i[4];
#pragma unroll
    for (int rr = 0; rr < 4; ++rr) {
      float ys = (float)y - sv4[rr];
      float fy = floorf(ys);
      float wfr = ys - fy;
      int i0 = (int)fy;
      lw0[rr] = (i0 + 1 >= 0 && i0 + 1 <= HH) ? 1.0f - wfr : 0.0f;
      lw1[rr] = (i0 + 2 >= 0 && i0 + 2 <= HH) ? wfr : 0.0f;
      a0i[rr] = min(max(i0 + 1, 0), HH);
      a1i[rr] = min(max(i0 + 2, 0), HH);
    }
#pragma unroll
    for (int ct = 0; ct < 2; ++ct) {
      f32x4 A = ct ? acc1 : acc0;
      int ch = (2 * p + ct) * 16 + l15;
      f32x4 res;
#pragma unroll
      for (int rr = 0; rr < 4; ++rr) {
        int px = px0 + rr;
        float v0 = bf2f(c2[((size_t)(b * C2R + a0i[rr]) * WW + px) * CC + ch]);
        float v1 = bf2f(c2[((size_t)(b * C2R + a1i[rr]) * WW + px) * CC + ch]);
        res[rr] = fminf(A[rr], lw0[rr] * v0 + lw1[rr] * v1);
      }
      *(f32x4*)(out + ((size_t)(b * CC + ch) * HH + y) * WW + px0) = res;
    }
  }
}

// ---------------------------------------------------------------------------
extern "C" void kernel_launch(void* const* d_in, const int* in_sizes, int n_in,
                              void* d_out, int out_size, void* d_ws, size_t ws_size,
                              hipStream_t stream) {
  const float* x = (const float*)d_in[0];
  const float* Wt = (const float*)d_in[1];
  float* out = (float*)d_out;

  char* ws = (char*)d_ws;
  float* s = (float*)ws;                                   // 1,048,576 B
  unsigned short* Wp = (unsigned short*)(ws + 1048576);    //    73,728 B
  unsigned short* xn = (unsigned short*)(ws + 1122304);    // 33,554,432 B
  unsigned short* c2 = (unsigned short*)(ws + 34676736);   // 33,685,504 B -> 68.4 MB

  k_pack<<<dim3(HH, BB), 256, 0, stream>>>(x, s, xn);
  k_wpack<<<dim3(18), 256, 0, stream>>>(Wt, Wp);
  k_lower<<<dim3(C2R, BB), 256, 0, stream>>>(xn, Wp, s, c2);
  k_final<<<dim3(HH, BB), 256, 0, stream>>>(xn, Wp, s, c2, out);
}